// Round 4
// baseline (1760.908 us; speedup 1.0000x reference)
//
#include <hip/hip_runtime.h>

#define D      128
#define NINIT  100000
#define LVLS   64
#define M      4096
#define NRULES 256
#define NTOT   (NINIT + LVLS * M)
#define NBLK   256
#define BLOCK  512
#define CHUNK  64          // max node rows staged per level pass (Poisson(16): P(>64)~0)

typedef __attribute__((ext_vector_type(8))) short short8;   // 8 bf16 = 4 VGPRs
typedef __attribute__((ext_vector_type(4))) float floatx4;  // MFMA accumulator

__device__ __forceinline__ unsigned short f2bf(float x) {  // RNE fp32->bf16
  unsigned u = __float_as_uint(x);
  u += 0x7fffu + ((u >> 16) & 1u);
  return (unsigned short)(u >> 16);
}

// ---------------------------------------------------------------------------
// ws layout (bytes):
//   0   : bar_cnt (unsigned)        128 : bar_gen (unsigned)
//   192 : sums[2] fp32
//   256 : store bf16 [NTOT][128]    (92,708,864 B)
//   SI  : sorted_idx int [LVLS][M]  (1,048,576 B)
//   RO  : rule_off int [LVLS][257]
// ---------------------------------------------------------------------------
#define ST_OFF 256
#define SI_OFF (ST_OFF + (size_t)NTOT * D * 2)
#define RO_OFF (SI_OFF + (size_t)LVLS * M * 4)

__device__ __forceinline__ void grid_sync(unsigned* bar_cnt, unsigned* bar_gen,
                                          unsigned target) {
  __syncthreads();
  if (threadIdx.x == 0) {
    unsigned arrived = __hip_atomic_fetch_add(bar_cnt, 1u, __ATOMIC_ACQ_REL,
                                              __HIP_MEMORY_SCOPE_AGENT);
    if (arrived == NBLK - 1) {
      __hip_atomic_store(bar_cnt, 0u, __ATOMIC_RELAXED, __HIP_MEMORY_SCOPE_AGENT);
      __hip_atomic_store(bar_gen, target, __ATOMIC_RELEASE, __HIP_MEMORY_SCOPE_AGENT);
    } else {
      while (__hip_atomic_load(bar_gen, __ATOMIC_ACQUIRE,
                               __HIP_MEMORY_SCOPE_AGENT) < target)
        __builtin_amdgcn_s_sleep(1);
    }
  }
  __syncthreads();
}

__device__ __forceinline__ float softplusf(float x) {
  return fmaxf(x, 0.f) + log1pf(expf(-fabsf(x)));
}

__global__ __launch_bounds__(BLOCK) void fused_kernel(
    const float* __restrict__ thax_table, const float* __restrict__ sine_table,
    const float* __restrict__ rule_W, const float* __restrict__ rule_b,
    const float* __restrict__ eval_w, const float* __restrict__ eval_b,
    const float* __restrict__ pos_vals, const float* __restrict__ neg_vals,
    const int* __restrict__ init_thax, const int* __restrict__ init_sine,
    const int* __restrict__ parents, const int* __restrict__ rules,
    float* __restrict__ out, char* __restrict__ ws) {
  __shared__ __align__(16) char smem_raw[CHUNK * 264 * 2];  // 33792 B

  unsigned* bar_cnt = (unsigned*)ws;
  unsigned* bar_gen = (unsigned*)(ws + 128);
  float* sums = (float*)(ws + 192);
  unsigned short* store = (unsigned short*)(ws + ST_OFF);
  int* sorted_idx = (int*)(ws + SI_OFF);
  int* rule_off = (int*)(ws + RO_OFF);

  const int tid = threadIdx.x;
  const int r = blockIdx.x;
  const int wave = tid >> 6, lane = tid & 63;
  const int col = (wave << 4) + (lane & 15);

  // ---- pre-phase A: counting-sort nodes by rule (blocks 0..63, level=blockIdx) ----
  if (r < LVLS) {
    int* cnt = (int*)smem_raw;        // 256 ints
    int* base = cnt + NRULES;         // 257 ints
    const int* rl = rules + (size_t)r * M;
    if (tid < NRULES) cnt[tid] = 0;
    __syncthreads();
    for (int m = tid; m < M; m += BLOCK) atomicAdd(&cnt[rl[m]], 1);
    __syncthreads();
    if (tid == 0) {
      int run = 0;
      for (int q = 0; q < NRULES; ++q) { base[q] = run; run += cnt[q]; }
      base[NRULES] = run;
    }
    __syncthreads();
    if (tid <= NRULES) rule_off[(size_t)r * (NRULES + 1) + tid] = base[tid];
    if (tid < NRULES) cnt[tid] = base[tid];
    __syncthreads();
    for (int m = tid; m < M; m += BLOCK) {
      int p = atomicAdd(&cnt[rl[m]], 1);
      sorted_idx[(size_t)r * M + p] = m;
    }
  }

  // ---- pre-phase B: init embeddings (all blocks, grid-stride) ----
  for (int idx = r * BLOCK + tid; idx < NINIT * 16; idx += NBLK * BLOCK) {
    int node = idx >> 4, seg = idx & 15;
    const float4* t = (const float4*)(thax_table + (size_t)init_thax[node] * D) + seg * 2;
    const float4* s = (const float4*)(sine_table + (size_t)init_sine[node] * D) + seg * 2;
    float4 a0 = t[0], a1 = t[1], b0 = s[0], b1 = s[1];
    float v[8] = {a0.x + b0.x, a0.y + b0.y, a0.z + b0.z, a0.w + b0.w,
                  a1.x + b1.x, a1.y + b1.y, a1.z + b1.z, a1.w + b1.w};
    uint4 pk;
    pk.x = (unsigned)f2bf(v[0]) | ((unsigned)f2bf(v[1]) << 16);
    pk.y = (unsigned)f2bf(v[2]) | ((unsigned)f2bf(v[3]) << 16);
    pk.z = (unsigned)f2bf(v[4]) | ((unsigned)f2bf(v[5]) << 16);
    pk.w = (unsigned)f2bf(v[6]) | ((unsigned)f2bf(v[7]) << 16);
    *(uint4*)(store + (size_t)node * D + seg * 8) = pk;
  }

  // ---- pre-phase C: pos/neg sums (all blocks) ----
  {
    float sp = 0.f, sn = 0.f;
    for (int i = r * BLOCK + tid; i < NTOT; i += NBLK * BLOCK) {
      sp += pos_vals[i];
      sn += neg_vals[i];
    }
    for (int m = 32; m; m >>= 1) {
      sp += __shfl_xor(sp, m, 64);
      sn += __shfl_xor(sn, m, 64);
    }
    __syncthreads();  // smem_raw reuse (sort done)
    float* sred = (float*)(smem_raw + 8192);
    if (lane == 0) { sred[wave * 2] = sp; sred[wave * 2 + 1] = sn; }
    __syncthreads();
    if (tid == 0) {
      float tp = 0.f, tn = 0.f;
      for (int w = 0; w < 8; ++w) { tp += sred[w * 2]; tn += sred[w * 2 + 1]; }
      atomicAdd(&sums[0], tp);
      atomicAdd(&sums[1], tn);
    }
  }

  // ---- pre-phase D: weight frags fp32 -> bf16, held in VGPRs for all levels ----
  short8 bf[8];
  {
    const float* Wr = rule_W + (size_t)r * (2 * D * D);
#pragma unroll
    for (int ks = 0; ks < 8; ++ks) {
      int krow = ks * 32 + (lane >> 4) * 8;
      unsigned short v[8];
#pragma unroll
      for (int j = 0; j < 8; ++j) v[j] = f2bf(Wr[(size_t)(krow + j) * D + col]);
      union { unsigned u[4]; short8 s; } c;
      c.u[0] = (unsigned)v[0] | ((unsigned)v[1] << 16);
      c.u[1] = (unsigned)v[2] | ((unsigned)v[3] << 16);
      c.u[2] = (unsigned)v[4] | ((unsigned)v[5] << 16);
      c.u[3] = (unsigned)v[6] | ((unsigned)v[7] << 16);
      bf[ks] = c.s;
    }
  }
  const float bias = rule_b[r * D + col];

  // ---- level loop ----
  unsigned short* pe = (unsigned short*)smem_raw;  // [CHUNK][264] padded rows
  unsigned gen = 0;
  for (int l = 0; l < LVLS; ++l) {
    grid_sync(bar_cnt, bar_gen, ++gen);  // level l-1 (or pre-phase) now visible
    const int* ro = rule_off + (size_t)l * (NRULES + 1);
    const int off0 = ro[r];
    const int cnt = ro[r + 1] - off0;
    const int* sidx = sorted_idx + (size_t)l * M;
    const int* par_l = parents + (size_t)l * M * 2;
    const int n_base = NINIT + l * M;

    for (int c0 = 0; c0 < cnt; c0 += CHUNK) {
      const int chunk_n = min(CHUNK, cnt - c0);
      __syncthreads();  // pe reuse
      for (int e = tid; e < chunk_n * 32; e += BLOCK) {
        int j = e >> 5, seg = e & 31;
        int sid = sidx[off0 + c0 + j];
        int p = par_l[sid * 2 + (seg >> 4)];
        uint4 d = *(const uint4*)(store + (size_t)p * D + (seg & 15) * 8);
        *(uint4*)(pe + j * 264 + seg * 8) = d;
      }
      __syncthreads();

      for (int st = 0; st * 16 < chunk_n; ++st) {
        floatx4 acc = {0.f, 0.f, 0.f, 0.f};
#pragma unroll
        for (int ks = 0; ks < 8; ++ks) {
          short8 a = *(const short8*)(pe + (st * 16 + (lane & 15)) * 264 +
                                      ks * 32 + (lane >> 4) * 8);
          acc = __builtin_amdgcn_mfma_f32_16x16x32_bf16(a, bf[ks], acc, 0, 0, 0);
        }
#pragma unroll
        for (int reg = 0; reg < 4; ++reg) {
          int gj = c0 + st * 16 + (lane >> 4) * 4 + reg;
          if (gj < cnt) {
            int sid = sidx[off0 + gj];
            float v = acc[reg] + bias;
            store[(size_t)(n_base + sid) * D + col] = f2bf(v > 0.f ? v : 0.f);
          }
        }
      }
    }
  }
  grid_sync(bar_cnt, bar_gen, ++gen);  // final level visible

  // ---- loss phase ----
  {
    float a_loss = 0.f, a_pos = 0.f, a_neg = 0.f;
    const float pw = sums[1] / sums[0];
    const float eb = eval_b[0];
    const float4* wv = (const float4*)eval_w;

    for (int node = r * BLOCK + tid; node < NTOT; node += NBLK * BLOCK) {
      const uint4* v = (const uint4*)(store + (size_t)node * D);
      float dot = 0.f;
#pragma unroll
      for (int k = 0; k < 16; ++k) {
        uint4 u = v[k];
        float4 w0 = wv[k * 2], w1 = wv[k * 2 + 1];
        dot += __uint_as_float(u.x << 16) * w0.x +
               __uint_as_float(u.x & 0xffff0000u) * w0.y +
               __uint_as_float(u.y << 16) * w0.z +
               __uint_as_float(u.y & 0xffff0000u) * w0.w +
               __uint_as_float(u.z << 16) * w1.x +
               __uint_as_float(u.z & 0xffff0000u) * w1.y +
               __uint_as_float(u.w << 16) * w1.z +
               __uint_as_float(u.w & 0xffff0000u) * w1.w;
      }
      float logit = dot + eb;
      float p = pos_vals[node], n = neg_vals[node];
      float tot = p + n, y = p / tot;
      a_loss += tot * (pw * y * softplusf(-logit) + (1.f - y) * softplusf(logit));
      if (logit >= 0.f) a_pos += p; else a_neg += n;
    }
    for (int m = 32; m; m >>= 1) {
      a_loss += __shfl_xor(a_loss, m, 64);
      a_pos  += __shfl_xor(a_pos,  m, 64);
      a_neg  += __shfl_xor(a_neg,  m, 64);
    }
    __syncthreads();  // pe no longer read
    float* racc = (float*)smem_raw;
    if (tid == 0) { racc[0] = 0.f; racc[1] = 0.f; racc[2] = 0.f; }
    __syncthreads();
    if (lane == 0) {
      atomicAdd(&racc[0], a_loss);
      atomicAdd(&racc[1], a_pos);
      atomicAdd(&racc[2], a_neg);
    }
    __syncthreads();
    if (tid == 0) {
      atomicAdd(&out[0], racc[0]);
      atomicAdd(&out[1], racc[1]);
      atomicAdd(&out[2], racc[2]);
    }
  }
}

extern "C" void kernel_launch(void* const* d_in, const int* in_sizes, int n_in,
                              void* d_out, int out_size, void* d_ws, size_t ws_size,
                              hipStream_t stream) {
  const float* thax_table = (const float*)d_in[0];
  const float* sine_table = (const float*)d_in[1];
  const float* rule_W     = (const float*)d_in[2];
  const float* rule_b     = (const float*)d_in[3];
  const float* eval_w     = (const float*)d_in[4];
  const float* eval_b     = (const float*)d_in[5];
  const float* pos_vals   = (const float*)d_in[6];
  const float* neg_vals   = (const float*)d_in[7];
  const int*   init_thax  = (const int*)d_in[8];
  const int*   init_sine  = (const int*)d_in[9];
  const int*   parents    = (const int*)d_in[10];
  const int*   rules      = (const int*)d_in[11];

  hipMemsetAsync(d_out, 0, 3 * sizeof(float), stream);
  hipMemsetAsync(d_ws, 0, 256, stream);  // barrier state + sums

  fused_kernel<<<NBLK, BLOCK, 0, stream>>>(
      thax_table, sine_table, rule_W, rule_b, eval_w, eval_b,
      pos_vals, neg_vals, init_thax, init_sine, parents, rules,
      (float*)d_out, (char*)d_ws);
}

// Round 5
// 752.664 us; speedup vs baseline: 2.3396x; 2.3396x over previous
//
#include <hip/hip_runtime.h>

#define D      128
#define NINIT  100000
#define LVLS   64
#define M      4096
#define NRULES 256
#define NTOT   (NINIT + LVLS * M)

typedef __attribute__((ext_vector_type(8))) short short8;   // 8 bf16 = 4 VGPRs
typedef __attribute__((ext_vector_type(4))) float floatx4;  // MFMA accumulator

__device__ __forceinline__ unsigned short f2bf(float x) {  // RNE fp32->bf16
  unsigned u = __float_as_uint(x);
  u += 0x7fffu + ((u >> 16) & 1u);
  return (unsigned short)(u >> 16);
}

// ---------------------------------------------------------------------------
// ws layout (bytes):
//   0      : sums[2] fp32
//   256    : store bf16 [NTOT][128]           (92,708,864 B)
//   WF_OFF : Wfrag bf16 [NRULES][32768]       (16,777,216 B)  frag-linear
//   SI_OFF : sorted_idx int [LVLS][M]         (1,048,576 B)
// ---------------------------------------------------------------------------
#define ST_OFF 256
#define WF_OFF (ST_OFF + (size_t)NTOT * D * 2)
#define SI_OFF (WF_OFF + (size_t)NRULES * 2 * D * D * 2)

// One-time: rule_W fp32 [256][256][128] -> frag-linear bf16.
// Frag element (ks, ct, lane, j) = W[ks*32 + (lane>>4)*8 + j][ct*16 + (lane&15)]
// at Wfrag[r][((ks*8+ct)*64 + lane)*8 + j].
__global__ __launch_bounds__(256) void wprep_kernel(
    const float* __restrict__ W, unsigned short* __restrict__ Wfrag) {
  const int r = blockIdx.x;
  const int wave = threadIdx.x >> 6, lane = threadIdx.x & 63;
  const float* Wr = W + (size_t)r * (2 * D * D);
  unsigned short* out = Wfrag + (size_t)r * (2 * D * D);
  for (int f = wave; f < 64; f += 4) {
    int ks = f >> 3, ct = f & 7;
    int krow = ks * 32 + (lane >> 4) * 8;
    int col = ct * 16 + (lane & 15);
    unsigned short v[8];
#pragma unroll
    for (int j = 0; j < 8; ++j) v[j] = f2bf(Wr[(size_t)(krow + j) * D + col]);
    uint4 pk;
    pk.x = (unsigned)v[0] | ((unsigned)v[1] << 16);
    pk.y = (unsigned)v[2] | ((unsigned)v[3] << 16);
    pk.z = (unsigned)v[4] | ((unsigned)v[5] << 16);
    pk.w = (unsigned)v[6] | ((unsigned)v[7] << 16);
    *(uint4*)(out + ((size_t)f * 64 + lane) * 8) = pk;
  }
}

// One-time: counting-sort nodes by rule, per level (block = level).
__global__ __launch_bounds__(256) void sort_kernel(
    const int* __restrict__ rules, int* __restrict__ sorted_idx) {
  __shared__ int cnt[NRULES];
  __shared__ int base[NRULES];
  const int l = blockIdx.x, t = threadIdx.x;
  const int* rl = rules + (size_t)l * M;
  cnt[t] = 0;
  __syncthreads();
  for (int m = t; m < M; m += 256) atomicAdd(&cnt[rl[m]], 1);
  __syncthreads();
  if (t == 0) {
    int run = 0;
    for (int r = 0; r < NRULES; ++r) { base[r] = run; run += cnt[r]; }
  }
  __syncthreads();
  cnt[t] = base[t];
  __syncthreads();
  for (int m = t; m < M; m += 256) {
    int p = atomicAdd(&cnt[rl[m]], 1);
    sorted_idx[(size_t)l * M + p] = m;
  }
}

__global__ __launch_bounds__(256) void init_kernel(
    const float* __restrict__ thax_table, const float* __restrict__ sine_table,
    const int* __restrict__ init_thax, const int* __restrict__ init_sine,
    unsigned short* __restrict__ store) {
  int idx = blockIdx.x * 256 + threadIdx.x;  // (node, 8-elem segment)
  int node = idx >> 4, seg = idx & 15;
  if (node >= NINIT) return;
  const float4* t = (const float4*)(thax_table + (size_t)init_thax[node] * D) + seg * 2;
  const float4* s = (const float4*)(sine_table + (size_t)init_sine[node] * D) + seg * 2;
  float4 a0 = t[0], a1 = t[1], b0 = s[0], b1 = s[1];
  float v[8] = {a0.x + b0.x, a0.y + b0.y, a0.z + b0.z, a0.w + b0.w,
                a1.x + b1.x, a1.y + b1.y, a1.z + b1.z, a1.w + b1.w};
  uint4 pk;
  pk.x = (unsigned)f2bf(v[0]) | ((unsigned)f2bf(v[1]) << 16);
  pk.y = (unsigned)f2bf(v[2]) | ((unsigned)f2bf(v[3]) << 16);
  pk.z = (unsigned)f2bf(v[4]) | ((unsigned)f2bf(v[5]) << 16);
  pk.w = (unsigned)f2bf(v[6]) | ((unsigned)f2bf(v[7]) << 16);
  *(uint4*)(store + (size_t)node * D + seg * 8) = pk;
}

__global__ __launch_bounds__(256) void sum_kernel(
    const float* __restrict__ pos, const float* __restrict__ neg,
    float* __restrict__ sums) {
  float sp = 0.f, sn = 0.f;
  for (int i = blockIdx.x * 256 + threadIdx.x; i < NTOT; i += gridDim.x * 256) {
    sp += pos[i];
    sn += neg[i];
  }
  for (int m = 32; m; m >>= 1) {
    sp += __shfl_xor(sp, m, 64);
    sn += __shfl_xor(sn, m, 64);
  }
  if ((threadIdx.x & 63) == 0) {
    atomicAdd(&sums[0], sp);
    atomicAdd(&sums[1], sn);
  }
}

// Block = one 16-node tile of the rule-sorted order (grid = M/16 = 256,
// perfectly balanced). 512 thr = 8 waves; wave w owns output cols [16w,16w+16).
// Single __syncthreads per level: stage 32 parent rows (all loads in flight)
// + prefetch span-0 B-frags, then span-loop MFMAs.
__global__ __launch_bounds__(512) void level_tile_kernel(
    unsigned short* __restrict__ store, const int* __restrict__ parents,
    const int* __restrict__ rules_l, const int* __restrict__ sorted_idx_l,
    const unsigned short* __restrict__ Wfrag, const float* __restrict__ Bv,
    int n_base) {
  __shared__ __align__(16) unsigned short pe[16 * 264];  // padded rows: 2-way max
  __shared__ int s_sid[16];
  __shared__ int s_rule[16];

  const int tid = threadIdx.x;
  const int wave = tid >> 6, lane = tid & 63;
  const int col = (wave << 4) + (lane & 15);
  const int b = blockIdx.x;

  // ---- stage: row j = concat(parent0, parent1) of sorted node 16b+j ----
  {
    int j = tid >> 5, seg = tid & 31;
    int sid = sorted_idx_l[b * 16 + j];  // 32-way broadcast load
    if (seg == 0) { s_sid[j] = sid; s_rule[j] = rules_l[sid]; }
    int p = parents[sid * 2 + (seg >> 4)];
    uint4 d = *(const uint4*)(store + (size_t)p * D + (seg & 15) * 8);
    *(uint4*)(pe + j * 264 + seg * 8) = d;
  }

  // ---- prefetch span-0 B-frags (overlaps the staging chain) ----
  int cur_rule = rules_l[sorted_idx_l[b * 16]];
  short8 bf[8];
#pragma unroll
  for (int ks = 0; ks < 8; ++ks)
    bf[ks] = *(const short8*)(Wfrag + (size_t)cur_rule * (2 * D * D) +
                              (((size_t)ks * 8 + wave) * 64 + lane) * 8);
  float bias = Bv[cur_rule * D + col];

  __syncthreads();

  // ---- span loop (tiles span ~2 rules on average) ----
  int j0 = 0;
  while (j0 < 16) {
    int r = s_rule[j0];
    int e = j0 + 1;
    while (e < 16 && s_rule[e] == r) ++e;
    if (r != cur_rule) {
#pragma unroll
      for (int ks = 0; ks < 8; ++ks)
        bf[ks] = *(const short8*)(Wfrag + (size_t)r * (2 * D * D) +
                                  (((size_t)ks * 8 + wave) * 64 + lane) * 8);
      bias = Bv[r * D + col];
      cur_rule = r;
    }
    floatx4 acc = {0.f, 0.f, 0.f, 0.f};
#pragma unroll
    for (int ks = 0; ks < 8; ++ks) {
      short8 a = *(const short8*)(pe + (lane & 15) * 264 + ks * 32 +
                                  (lane >> 4) * 8);
      acc = __builtin_amdgcn_mfma_f32_16x16x32_bf16(a, bf[ks], acc, 0, 0, 0);
    }
#pragma unroll
    for (int reg = 0; reg < 4; ++reg) {
      int row = (lane >> 4) * 4 + reg;
      if (row >= j0 && row < e) {
        float v = acc[reg] + bias;
        store[(size_t)(n_base + s_sid[row]) * D + col] = f2bf(v > 0.f ? v : 0.f);
      }
    }
    j0 = e;
  }
}

__device__ __forceinline__ float softplusf(float x) {
  return fmaxf(x, 0.f) + log1pf(expf(-fabsf(x)));
}

__global__ __launch_bounds__(1024) void loss_kernel(
    const unsigned short* __restrict__ store, const float* __restrict__ eval_w,
    const float* __restrict__ eval_b, const float* __restrict__ pos,
    const float* __restrict__ neg, const float* __restrict__ sums,
    float* __restrict__ out) {
  float a_loss = 0.f, a_pos = 0.f, a_neg = 0.f;
  const float pw = sums[1] / sums[0];
  const float eb = eval_b[0];
  const float4* wv = (const float4*)eval_w;

  for (int node = blockIdx.x * 1024 + threadIdx.x; node < NTOT;
       node += gridDim.x * 1024) {
    const uint4* v = (const uint4*)(store + (size_t)node * D);
    float dot = 0.f;
#pragma unroll
    for (int k = 0; k < 16; ++k) {
      uint4 u = v[k];
      float4 w0 = wv[k * 2], w1 = wv[k * 2 + 1];
      dot += __uint_as_float(u.x << 16) * w0.x +
             __uint_as_float(u.x & 0xffff0000u) * w0.y +
             __uint_as_float(u.y << 16) * w0.z +
             __uint_as_float(u.y & 0xffff0000u) * w0.w +
             __uint_as_float(u.z << 16) * w1.x +
             __uint_as_float(u.z & 0xffff0000u) * w1.y +
             __uint_as_float(u.w << 16) * w1.z +
             __uint_as_float(u.w & 0xffff0000u) * w1.w;
    }
    float logit = dot + eb;
    float p = pos[node], n = neg[node];
    float tot = p + n, y = p / tot;
    a_loss += tot * (pw * y * softplusf(-logit) + (1.f - y) * softplusf(logit));
    if (logit >= 0.f) a_pos += p; else a_neg += n;
  }

  for (int m = 32; m; m >>= 1) {
    a_loss += __shfl_xor(a_loss, m, 64);
    a_pos  += __shfl_xor(a_pos,  m, 64);
    a_neg  += __shfl_xor(a_neg,  m, 64);
  }
  __shared__ float racc[3];
  if (threadIdx.x == 0) { racc[0] = 0.f; racc[1] = 0.f; racc[2] = 0.f; }
  __syncthreads();
  if ((threadIdx.x & 63) == 0) {
    atomicAdd(&racc[0], a_loss);
    atomicAdd(&racc[1], a_pos);
    atomicAdd(&racc[2], a_neg);
  }
  __syncthreads();
  if (threadIdx.x == 0) {
    atomicAdd(&out[0], racc[0]);
    atomicAdd(&out[1], racc[1]);
    atomicAdd(&out[2], racc[2]);
  }
}

extern "C" void kernel_launch(void* const* d_in, const int* in_sizes, int n_in,
                              void* d_out, int out_size, void* d_ws, size_t ws_size,
                              hipStream_t stream) {
  const float* thax_table = (const float*)d_in[0];
  const float* sine_table = (const float*)d_in[1];
  const float* rule_W     = (const float*)d_in[2];
  const float* rule_b     = (const float*)d_in[3];
  const float* eval_w     = (const float*)d_in[4];
  const float* eval_b     = (const float*)d_in[5];
  const float* pos_vals   = (const float*)d_in[6];
  const float* neg_vals   = (const float*)d_in[7];
  const int*   init_thax  = (const int*)d_in[8];
  const int*   init_sine  = (const int*)d_in[9];
  const int*   parents    = (const int*)d_in[10];
  const int*   rules      = (const int*)d_in[11];

  float* out = (float*)d_out;
  char* ws = (char*)d_ws;
  float* sums = (float*)ws;
  unsigned short* store = (unsigned short*)(ws + ST_OFF);
  unsigned short* Wfrag = (unsigned short*)(ws + WF_OFF);
  int* sorted_idx = (int*)(ws + SI_OFF);

  hipMemsetAsync(d_out, 0, 3 * sizeof(float), stream);
  hipMemsetAsync(d_ws, 0, 2 * sizeof(float), stream);

  wprep_kernel<<<NRULES, 256, 0, stream>>>(rule_W, Wfrag);
  sort_kernel<<<LVLS, 256, 0, stream>>>(rules, sorted_idx);
  init_kernel<<<(NINIT * 16 + 255) / 256, 256, 0, stream>>>(
      thax_table, sine_table, init_thax, init_sine, store);
  sum_kernel<<<256, 256, 0, stream>>>(pos_vals, neg_vals, sums);

  for (int l = 0; l < LVLS; ++l) {
    level_tile_kernel<<<M / 16, 512, 0, stream>>>(
        store, parents + (size_t)l * M * 2, rules + (size_t)l * M,
        sorted_idx + (size_t)l * M, Wfrag, rule_b, NINIT + l * M);
  }

  loss_kernel<<<512, 1024, 0, stream>>>(
      store, eval_w, eval_b, pos_vals, neg_vals, sums, out);
}